// Round 3
// 2355.258 us; speedup vs baseline: 1.0986x; 1.0986x over previous
//
#include <hip/hip_runtime.h>
#include <stdint.h>
#include <stddef.h>

// ---------- types / helpers ----------
typedef __attribute__((ext_vector_type(8))) short  short8;   // 8 bf16 (4 VGPRs)
typedef __attribute__((ext_vector_type(4))) float  floatx4;  // MFMA acc
typedef unsigned long long u64;

#define SENT 0xAAAAAAAAAAAAAAAAull   // ws poison pattern = our sentinel

static __device__ __forceinline__ float b2f(uint16_t h) {
  union { uint32_t u; float f; } v; v.u = ((uint32_t)h) << 16; return v.f;
}
static __device__ __forceinline__ uint16_t f2b(float f) {
  union { float f; uint32_t u; } v; v.f = f;
  uint32_t u = v.u;
  uint32_t r = u + 0x7FFFu + ((u >> 16) & 1u);   // RNE
  return (uint16_t)(r >> 16);
}
static __device__ __forceinline__ float sigm(float x)  { return 1.0f / (1.0f + __expf(-x)); }
static __device__ __forceinline__ float tanh_f(float x){ return 1.0f - 2.0f / (1.0f + __expf(2.0f * x)); }

static __device__ __forceinline__ floatx4 mfma16(short8 a, short8 b, floatx4 c) {
  return __builtin_amdgcn_mfma_f32_16x16x32_bf16(a, b, c, 0, 0, 0);
}
static __device__ __forceinline__ short8 cvt8(const float* p) {
  short8 r;
  #pragma unroll
  for (int i = 0; i < 8; ++i) r[i] = (short)f2b(p[i]);
  return r;
}

// ---------- exchange primitives ----------
// Stores: round-0-proven agent-scope atomic store (correct for any placement).
static __device__ __forceinline__ void st_h64(uint16_t* p, u64 v) {
  __hip_atomic_store((u64*)p, v, __ATOMIC_RELAXED, __HIP_MEMORY_SCOPE_AGENT);
}
static __device__ __forceinline__ u64 ld_h64(const u64* p) {
  return __hip_atomic_load(p, __ATOMIC_RELAXED, __HIP_MEMORY_SCOPE_AGENT);
}
// Fast poll pass: 8 loads issued back-to-back in ONE asm block, ONE
// s_waitcnt vmcnt(0). sc0 sc1 = system scope (bypasses L1+L2): strictly
// stronger than the agent-scope loads round 0 used, correct for any
// block->XCD placement. Round 0's per-word atomic loads cost ~8 serialized
// fabric round trips (~7200cy) per pass = the measured 3.25us/step.
static __device__ __forceinline__ void ld8_dev(const u64* p, u64* o) {
  asm volatile(
      "global_load_dwordx2 %0, %8, off sc0 sc1\n\t"
      "global_load_dwordx2 %1, %8, off offset:8 sc0 sc1\n\t"
      "global_load_dwordx2 %2, %8, off offset:16 sc0 sc1\n\t"
      "global_load_dwordx2 %3, %8, off offset:24 sc0 sc1\n\t"
      "global_load_dwordx2 %4, %8, off offset:32 sc0 sc1\n\t"
      "global_load_dwordx2 %5, %8, off offset:40 sc0 sc1\n\t"
      "global_load_dwordx2 %6, %8, off offset:48 sc0 sc1\n\t"
      "global_load_dwordx2 %7, %8, off offset:56 sc0 sc1\n\t"
      "s_waitcnt vmcnt(0)"
      : "=&v"(o[0]), "=&v"(o[1]), "=&v"(o[2]), "=&v"(o[3]),
        "=&v"(o[4]), "=&v"(o[5]), "=&v"(o[6]), "=&v"(o[7])
      : "v"(p)
      : "memory");
}
// 16 loads (two 64B groups), one wait
static __device__ __forceinline__ void ld16_dev(const u64* pa, const u64* pb, u64* oa, u64* ob) {
  asm volatile(
      "global_load_dwordx2 %0, %16, off sc0 sc1\n\t"
      "global_load_dwordx2 %1, %16, off offset:8 sc0 sc1\n\t"
      "global_load_dwordx2 %2, %16, off offset:16 sc0 sc1\n\t"
      "global_load_dwordx2 %3, %16, off offset:24 sc0 sc1\n\t"
      "global_load_dwordx2 %4, %16, off offset:32 sc0 sc1\n\t"
      "global_load_dwordx2 %5, %16, off offset:40 sc0 sc1\n\t"
      "global_load_dwordx2 %6, %16, off offset:48 sc0 sc1\n\t"
      "global_load_dwordx2 %7, %16, off offset:56 sc0 sc1\n\t"
      "global_load_dwordx2 %8, %17, off sc0 sc1\n\t"
      "global_load_dwordx2 %9, %17, off offset:8 sc0 sc1\n\t"
      "global_load_dwordx2 %10, %17, off offset:16 sc0 sc1\n\t"
      "global_load_dwordx2 %11, %17, off offset:24 sc0 sc1\n\t"
      "global_load_dwordx2 %12, %17, off offset:32 sc0 sc1\n\t"
      "global_load_dwordx2 %13, %17, off offset:40 sc0 sc1\n\t"
      "global_load_dwordx2 %14, %17, off offset:48 sc0 sc1\n\t"
      "global_load_dwordx2 %15, %17, off offset:56 sc0 sc1\n\t"
      "s_waitcnt vmcnt(0)"
      : "=&v"(oa[0]), "=&v"(oa[1]), "=&v"(oa[2]), "=&v"(oa[3]),
        "=&v"(oa[4]), "=&v"(oa[5]), "=&v"(oa[6]), "=&v"(oa[7]),
        "=&v"(ob[0]), "=&v"(ob[1]), "=&v"(ob[2]), "=&v"(ob[3]),
        "=&v"(ob[4]), "=&v"(ob[5]), "=&v"(ob[6]), "=&v"(ob[7])
      : "v"(pa), "v"(pb)
      : "memory");
}
// Poll with safety valve: every 256th pass uses the round-0-proven atomic
// loads. If the asm path ever misbehaved, the valve still observes data ->
// hang impossible (worst case: round-0 latency).
static __device__ __forceinline__ void poll8_dev(const u64* p, u64* o) {
  int it = 0;
  for (;;) {
    if ((++it & 255) == 0) {
      #pragma unroll
      for (int i = 0; i < 8; ++i) o[i] = ld_h64(p + i);
    } else {
      ld8_dev(p, o);
    }
    bool ok = true;
    #pragma unroll
    for (int i = 0; i < 8; ++i) ok &= (o[i] != SENT);
    if (ok) break;
    __builtin_amdgcn_s_sleep(1);
  }
}
static __device__ __forceinline__ void poll16_dev(const u64* pa, const u64* pb, u64* oa, u64* ob) {
  int it = 0;
  for (;;) {
    if ((++it & 255) == 0) {
      #pragma unroll
      for (int i = 0; i < 8; ++i) { oa[i] = ld_h64(pa + i); ob[i] = ld_h64(pb + i); }
    } else {
      ld16_dev(pa, pb, oa, ob);
    }
    bool ok = true;
    #pragma unroll
    for (int i = 0; i < 8; ++i) ok &= (oa[i] != SENT) & (ob[i] != SENT);
    if (ok) break;
    __builtin_amdgcn_s_sleep(1);
  }
}

#define H 256
#define FH 1024
#define BATCH 32
#define TSEQ 512
#define DSTEPS 64
#define ERING 8          // encoder h-slot ring depth (round-0 verified)

// =====================================================================
// Phase A GEMM (unchanged — correct since round 2 of prior session)
// =====================================================================
__global__ __launch_bounds__(256) void gemm_xw(
    const float* __restrict__ A, const float* __restrict__ W,
    const float* __restrict__ bias, void* __restrict__ Cout, int out_f32)
{
  const int K = 1024, N = 1024;
  __shared__ uint16_t Ah[64 * 40], Al[64 * 40];
  __shared__ uint16_t Wh[64 * 40], Wl[64 * 40];
  const int m0 = blockIdx.x * 64;
  const int n0 = blockIdx.y * 64;
  const int tid = threadIdx.x;
  const int lane = tid & 63, w = tid >> 6;
  const int wm = w & 1, wn = w >> 1;
  const int l15 = lane & 15, q4 = lane >> 4;
  const int ldrow = tid >> 2, ldk = (tid & 3) * 8;

  floatx4 acc[2][2];
  for (int i = 0; i < 2; ++i) for (int j = 0; j < 2; ++j) acc[i][j] = (floatx4){0.f,0.f,0.f,0.f};

  for (int kb = 0; kb < K; kb += 32) {
    float aa[8], ww[8];
    {
      const float4* ap = (const float4*)(A + (size_t)(m0 + ldrow) * K + kb + ldk);
      const float4* wp = (const float4*)(W + (size_t)(n0 + ldrow) * K + kb + ldk);
      *(float4*)(aa) = ap[0]; *(float4*)(aa + 4) = ap[1];
      *(float4*)(ww) = wp[0]; *(float4*)(ww + 4) = wp[1];
    }
    short8 ah, al, wh, wl;
    #pragma unroll
    for (int i = 0; i < 8; ++i) {
      uint16_t h = f2b(aa[i]); ah[i] = (short)h; al[i] = (short)f2b(aa[i] - b2f(h));
      uint16_t g = f2b(ww[i]); wh[i] = (short)g; wl[i] = (short)f2b(ww[i] - b2f(g));
    }
    __syncthreads();
    *(short8*)(Ah + ldrow * 40 + ldk) = ah;
    *(short8*)(Al + ldrow * 40 + ldk) = al;
    *(short8*)(Wh + ldrow * 40 + ldk) = wh;
    *(short8*)(Wl + ldrow * 40 + ldk) = wl;
    __syncthreads();
    short8 afh[2], afl[2], bfh[2], bfl[2];
    #pragma unroll
    for (int mt = 0; mt < 2; ++mt) {
      afh[mt] = *(const short8*)(Ah + (wm * 32 + mt * 16 + l15) * 40 + q4 * 8);
      afl[mt] = *(const short8*)(Al + (wm * 32 + mt * 16 + l15) * 40 + q4 * 8);
    }
    #pragma unroll
    for (int nt = 0; nt < 2; ++nt) {
      bfh[nt] = *(const short8*)(Wh + (wn * 32 + nt * 16 + l15) * 40 + q4 * 8);
      bfl[nt] = *(const short8*)(Wl + (wn * 32 + nt * 16 + l15) * 40 + q4 * 8);
    }
    #pragma unroll
    for (int mt = 0; mt < 2; ++mt)
      #pragma unroll
      for (int nt = 0; nt < 2; ++nt) {
        acc[mt][nt] = mfma16(afh[mt], bfh[nt], acc[mt][nt]);
        acc[mt][nt] = mfma16(afh[mt], bfl[nt], acc[mt][nt]);
        acc[mt][nt] = mfma16(afl[mt], bfh[nt], acc[mt][nt]);
      }
  }
  #pragma unroll
  for (int mt = 0; mt < 2; ++mt)
    #pragma unroll
    for (int nt = 0; nt < 2; ++nt) {
      const int col = n0 + wn * 32 + nt * 16 + l15;
      const float bv = bias[col];
      #pragma unroll
      for (int r = 0; r < 4; ++r) {
        const int row = m0 + wm * 32 + mt * 16 + q4 * 4 + r;
        const float v = acc[mt][nt][r] + bv;
        if (out_f32) ((float*)Cout)[(size_t)row * N + col] = v;
        else         ((uint16_t*)Cout)[(size_t)row * N + col] = f2b(v);
      }
    }
}

// =====================================================================
// Phase B: encoder recurrence. Grid = 16 WGs: d = blk>>3, q = blk&7.
// Round-0 verified structure + protocol; poll path batched (one vmcnt(0)
// per pass) + Xg prefetched one step ahead. Stores unchanged from round 0.
// =====================================================================
__global__ __launch_bounds__(256, 1) void enc_rnn(
    const void* __restrict__ XgF, const void* __restrict__ XgB, int xg_f32,
    const float* __restrict__ WhhF, const float* __restrict__ WhhB,
    uint16_t* __restrict__ hslots,    // [2 dir][ERING][32][256] bf16, poisoned
    uint16_t* __restrict__ hfin, float* __restrict__ cfin)
{
  const int d = blockIdx.x >> 3, q = blockIdx.x & 7;
  const void*  Xg  = d ? XgB : XgF;
  const float* Whh = d ? WhhB : WhhF;
  uint16_t* hsl = hslots + d * (ERING * BATCH * H);
  const int jOff = q * 32;
  const int tid = threadIdx.x, lane = tid & 63, w = tid >> 6;
  const int tt = w & 1, nt = w >> 1, l15 = lane & 15, q4 = lane >> 4;
  const int b = nt * 16 + l15;
  const int jg = jOff + tt * 16 + q4 * 4;

  __shared__ uint16_t hS[2][32 * 264];
  __shared__ float    xgS[2][32 * 132];

  short8 Af[4][8];
  #pragma unroll
  for (int g = 0; g < 4; ++g) {
    const int grow = g * H + jOff + tt * 16 + l15;
    #pragma unroll
    for (int ks = 0; ks < 8; ++ks)
      Af[g][ks] = cvt8(Whh + (size_t)grow * H + ks * 32 + q4 * 8);
  }
  for (int i = tid; i < 32 * 264; i += 256) hS[0][i] = 0;   // h_0 = 0

  float cc[4] = {0.f, 0.f, 0.f, 0.f};
  union HV { uint16_t u16[4]; u64 v; } hv; hv.v = 0ull;
  const int rb = tid >> 3, seg = tid & 7;
  const int cp = seg * 16;
  const int gge = cp >> 5, jj = cp & 31;

  float xv[16];
  auto ldxF = [&](int s2) {
    const int t2 = d ? (TSEQ - 1 - s2) : s2;
    const size_t bas = (size_t)(t2 * BATCH + rb) * FH + gge * H + jOff + jj;
    const float4* xs = (const float4*)((const float*)Xg + bas);
    *(float4*)(xv)      = xs[0]; *(float4*)(xv + 4)  = xs[1];
    *(float4*)(xv + 8)  = xs[2]; *(float4*)(xv + 12) = xs[3];
  };
  if (xg_f32) ldxF(0);

  for (int s = 0; s < TSEQ; ++s) {
    const int p = s & 1;
    // consume this step's Xg slice (prefetched at s-1) into LDS
    if (xg_f32) {
      #pragma unroll
      for (int i = 0; i < 16; ++i) xgS[p][rb * 132 + cp + i] = xv[i];
    } else {
      const int t = d ? (TSEQ - 1 - s) : s;
      const uint16_t* xs = (const uint16_t*)Xg +
          (size_t)(t * BATCH + rb) * FH + gge * H + jOff + jj;
      #pragma unroll
      for (int i = 0; i < 16; ++i) xgS[p][rb * 132 + cp + i] = b2f(xs[i]);
    }

    if (s > 0) {
      u64 tmp[8];
      const u64* ps = (const u64*)(hsl + ((s - 1) & (ERING - 1)) * (BATCH * H) + rb * H + seg * 32);
      poll8_dev(ps, tmp);
      #pragma unroll
      for (int i = 0; i < 8; ++i)
        *(u64*)(hS[p] + rb * 264 + seg * 32 + i * 4) = tmp[i];
    }
    if (s >= 2)   // re-poison own slice of slot s-2 for ring reuse
      st_h64(hsl + ((s - 2) & (ERING - 1)) * (BATCH * H) + b * H + jg, SENT);
    __syncthreads();
    if (xg_f32 && s + 1 < TSEQ) ldxF(s + 1);   // prefetch next step's Xg

    floatx4 a0 = {0.f,0.f,0.f,0.f}, a1 = a0, a2 = a0, a3 = a0;
    #pragma unroll
    for (int ks = 0; ks < 8; ++ks) {
      short8 bfv = *(const short8*)(hS[p] + b * 264 + ks * 32 + q4 * 8);
      a0 = mfma16(Af[0][ks], bfv, a0);
      a1 = mfma16(Af[1][ks], bfv, a1);
      a2 = mfma16(Af[2][ks], bfv, a2);
      a3 = mfma16(Af[3][ks], bfv, a3);
    }
    #pragma unroll
    for (int r = 0; r < 4; ++r) {
      const int jl = tt * 16 + q4 * 4 + r;
      const float gi = a0[r] + xgS[p][b * 132 +      jl];
      const float gf = a1[r] + xgS[p][b * 132 + 32 + jl];
      const float gc = a2[r] + xgS[p][b * 132 + 64 + jl];
      const float go = a3[r] + xgS[p][b * 132 + 96 + jl];
      const float cn2 = sigm(gf) * cc[r] + sigm(gi) * tanh_f(gc);
      cc[r] = cn2;
      hv.u16[r] = f2b(sigm(go) * tanh_f(cn2));
    }
    st_h64(hsl + (s & (ERING - 1)) * (BATCH * H) + b * H + jg, hv.v);
  }
  #pragma unroll
  for (int r = 0; r < 4; ++r) {
    hfin[d * (BATCH * H) + b * H + jg + r] = hv.u16[r];   // kernel boundary
    cfin[d * (BATCH * H) + b * H + jg + r] = cc[r];
  }
}

// =====================================================================
// Phase C: decoder, 2 layers x 64 steps. Grid = 16 WGs: L = blk>>3, q = blk&7.
// Write-once per-step slots (poisoned), data-is-the-flag polling.
// Both dependencies polled JOINTLY in one 16-load/one-wait pass.
// =====================================================================
__global__ __launch_bounds__(256, 1) void dec_rnn(
    const float* __restrict__ Wih0, const float* __restrict__ Whh0, const float* __restrict__ bb0,
    const float* __restrict__ Wih1, const float* __restrict__ Whh1, const float* __restrict__ bb1,
    const uint16_t* __restrict__ hfin, const float* __restrict__ cfin,
    uint16_t* __restrict__ h0slots,  // [64][32][256] bf16, poisoned
    uint16_t* __restrict__ h1slots,  // [64][32][256] bf16, poisoned
    float*    __restrict__ h1f)      // [64][32][256] f32 (plain)
{
  const int L = blockIdx.x >> 3, q = blockIdx.x & 7;
  const float* Wih = L ? Wih1 : Wih0;
  const float* Whh = L ? Whh1 : Whh0;
  const float* bs  = L ? bb1 : bb0;
  const int jOff = q * 32;
  const int tid = threadIdx.x, lane = tid & 63, w = tid >> 6;
  const int tt = w & 1, nt = w >> 1, l15 = lane & 15, q4 = lane >> 4;
  const int b = nt * 16 + l15;
  const int jg = jOff + tt * 16 + q4 * 4;

  __shared__ uint16_t xhS[2][32 * 528];

  short8 Af[4][16];
  #pragma unroll
  for (int g = 0; g < 4; ++g) {
    const int grow = g * H + jOff + tt * 16 + l15;
    #pragma unroll
    for (int ks = 0; ks < 8; ++ks) {
      Af[g][ks]     = cvt8(Wih + (size_t)grow * H + ks * 32 + q4 * 8);
      Af[g][8 + ks] = cvt8(Whh + (size_t)grow * H + ks * 32 + q4 * 8);
    }
  }
  float brg[4][4];
  #pragma unroll
  for (int g = 0; g < 4; ++g)
    #pragma unroll
    for (int r = 0; r < 4; ++r)
      brg[g][r] = bs[g * H + jOff + tt * 16 + q4 * 4 + r];

  float cc[4];
  #pragma unroll
  for (int r = 0; r < 4; ++r) cc[r] = cfin[L * (BATCH * H) + b * H + jg + r];

  const int rb = tid >> 3, seg = tid & 7;
  const size_t off = (size_t)rb * H + seg * 32;
  union HV { uint16_t u16[4]; u64 v; } hv; hv.v = 0ull;

  for (int t = 0; t < DSTEPS; ++t) {
    const int p = t & 1;
    u64 tx[8], th[8];
    if (t == 0) {
      // own-layer h from kernel boundary (plain loads)
      const u64* ph = (const u64*)(hfin + L * (BATCH * H) + off);
      #pragma unroll
      for (int i = 0; i < 8; ++i) th[i] = ph[i];
      if (L == 0) {
        #pragma unroll
        for (int i = 0; i < 8; ++i) tx[i] = 0ull;
      } else {
        poll8_dev((const u64*)(h0slots + (size_t)0 * (BATCH * H) + off), tx);
      }
    } else {
      const uint16_t* hb = (L ? h1slots : h0slots) + (size_t)(t - 1) * (BATCH * H);
      const uint16_t* xb = L ? (h0slots + (size_t)t * (BATCH * H))
                             : (h1slots + (size_t)(t - 1) * (BATCH * H));
      poll16_dev((const u64*)(hb + off), (const u64*)(xb + off), th, tx);
    }
    #pragma unroll
    for (int i = 0; i < 8; ++i) {
      *(u64*)(xhS[p] + rb * 528 + seg * 32 + i * 4) = tx[i];
      *(u64*)(xhS[p] + rb * 528 + 256 + seg * 32 + i * 4) = th[i];
    }
    __syncthreads();

    floatx4 a0 = {0.f,0.f,0.f,0.f}, a1 = a0, a2 = a0, a3 = a0;
    #pragma unroll
    for (int ks = 0; ks < 16; ++ks) {
      short8 bfv = *(const short8*)(xhS[p] + b * 528 + ks * 32 + q4 * 8);
      a0 = mfma16(Af[0][ks], bfv, a0);
      a1 = mfma16(Af[1][ks], bfv, a1);
      a2 = mfma16(Af[2][ks], bfv, a2);
      a3 = mfma16(Af[3][ks], bfv, a3);
    }
    float hval[4];
    #pragma unroll
    for (int r = 0; r < 4; ++r) {
      const float gi = a0[r] + brg[0][r];
      const float gf = a1[r] + brg[1][r];
      const float gc = a2[r] + brg[2][r];
      const float go = a3[r] + brg[3][r];
      const float cn2 = sigm(gf) * cc[r] + sigm(gi) * tanh_f(gc);
      cc[r] = cn2;
      hval[r] = sigm(go) * tanh_f(cn2);
      hv.u16[r] = f2b(hval[r]);
    }
    st_h64((L ? h1slots : h0slots) + (size_t)t * (BATCH * H) + b * H + jg, hv.v);
    if (L == 1) {
      float* df = h1f + (size_t)t * (BATCH * H) + b * H + jg;
      #pragma unroll
      for (int r = 0; r < 4; ++r) df[r] = hval[r];
    }
  }
}

// =====================================================================
// Phase D
// =====================================================================
__global__ __launch_bounds__(256) void out_proj(
    const float* __restrict__ h1f, const float* __restrict__ linW,
    const float* __restrict__ linb, float* __restrict__ out)
{
  const int idx = blockIdx.x * 256 + threadIdx.x;
  if (idx >= DSTEPS * BATCH * 3) return;
  const int v = idx % 3;
  const int tb = idx / 3;
  const float* hrow = h1f + (size_t)tb * H;
  const float* wrow = linW + (size_t)v * H;
  float s = linb[v];
  for (int k = 0; k < H; ++k) s += hrow[k] * wrow[k];
  out[idx] = s;
}

// =====================================================================
extern "C" void kernel_launch(void* const* d_in, const int* in_sizes, int n_in,
                              void* d_out, int out_size, void* d_ws, size_t ws_size,
                              hipStream_t stream) {
  (void)in_sizes; (void)n_in; (void)out_size;
  const float* cnn   = (const float*)d_in[0];
  const float* WihF  = (const float*)d_in[1];
  const float* WhhF  = (const float*)d_in[2];
  const float* bF    = (const float*)d_in[3];
  const float* WihB  = (const float*)d_in[4];
  const float* WhhB  = (const float*)d_in[5];
  const float* bB    = (const float*)d_in[6];
  const float* Wih0  = (const float*)d_in[7];
  const float* Whh0  = (const float*)d_in[8];
  const float* b0    = (const float*)d_in[9];
  const float* Wih1  = (const float*)d_in[10];
  const float* Whh1  = (const float*)d_in[11];
  const float* b1    = (const float*)d_in[12];
  const float* linW  = (const float*)d_in[13];
  const float* linb  = (const float*)d_in[14];

  const size_t XG_ELEMS = (size_t)TSEQ * BATCH * FH;   // 16 Mi elems / dir
  // small region: hslotsE 262144 | h0slots 1 MB | h1slots 1 MB | hfin 32K | cfin 64K
  const size_t SMALL = 2457600;
  const int xg_f32 = (ws_size >= 2 * XG_ELEMS * 4 + SMALL) ? 1 : 0;
  const size_t S = XG_ELEMS * (xg_f32 ? 4 : 2);

  uint8_t* ws = (uint8_t*)d_ws;
  void*     XgF    = (void*)(ws);
  void*     XgB    = (void*)(ws + S);
  float*    h1f    = (float*)(ws + S);                 // overlaps XgB: dead after enc
  uint8_t*  base   = ws + 2 * S;
  uint16_t* hslotsE = (uint16_t*)(base);               // 2*8*8192*2   = 262144
  uint16_t* h0slots = (uint16_t*)(base + 262144);      // 64*8192*2    = 1048576
  uint16_t* h1slots = (uint16_t*)(base + 1310720);     // 1048576  (poison end 2359296)
  uint16_t* hfin    = (uint16_t*)(base + 2359296);     // 32768
  float*    cfin    = (float*)(base + 2392064);        // 65536 (end 2457600)

  // sentinel-poison all exchange slots (required every launch, incl. replays)
  hipMemsetAsync(base, 0xAA, 2359296, stream);

  gemm_xw<<<dim3(256, 16), 256, 0, stream>>>(cnn, WihF, bF, XgF, xg_f32);
  gemm_xw<<<dim3(256, 16), 256, 0, stream>>>(cnn, WihB, bB, XgB, xg_f32);
  enc_rnn<<<16, 256, 0, stream>>>(XgF, XgB, xg_f32, WhhF, WhhB,
                                  hslotsE, hfin, cfin);
  dec_rnn<<<16, 256, 0, stream>>>(Wih0, Whh0, b0, Wih1, Whh1, b1,
                                  hfin, cfin, h0slots, h1slots, h1f);
  out_proj<<<24, 256, 0, stream>>>(h1f, linW, linb, (float*)d_out);
}